// Round 1
// baseline (1935.788 us; speedup 1.0000x reference)
//
#include <hip/hip_runtime.h>
#include <cstdint>
#include <cstddef>

// ---------------------------------------------------------------------------
// GCN: 3 layers.  out = A_hat @ (h @ W) + b  per layer, A_hat = D^-1/2 (A+I) D^-1/2
// Baseline: fp32 tiled GEMM + atomic scatter aggregation.
// ---------------------------------------------------------------------------

static inline int cdiv_i(long a, long b) { return (int)((a + b - 1) / b); }

// Detect whether edge_index buffer is int64 (JAX x64 on) or int32 (default).
// int64 little-endian values < N look like (val, 0) uint pairs; int32 data has
// nonzero "hi" words with overwhelming probability over 64 samples.
__global__ void detect_fmt_kernel(const unsigned int* __restrict__ raw, int n_nodes,
                                  int* __restrict__ flag) {
    if (blockIdx.x == 0 && threadIdx.x == 0) {
        int is64 = 1;
        for (int i = 0; i < 64; ++i) {
            unsigned lo = raw[2 * i], hi = raw[2 * i + 1];
            if (hi != 0u || lo >= (unsigned)n_nodes) { is64 = 0; break; }
        }
        *flag = is64;
    }
}

__global__ void edges_to_i32_kernel(const void* __restrict__ raw, int* __restrict__ out,
                                    int twoE, const int* __restrict__ flag) {
    const int f = *flag;
    for (long i = blockIdx.x * (long)blockDim.x + threadIdx.x; i < twoE;
         i += (long)gridDim.x * blockDim.x) {
        out[i] = f ? (int)(((const long long*)raw)[i]) : ((const int*)raw)[i];
    }
}

__global__ void deg_init_kernel(float* __restrict__ deg, int n) {
    for (long i = blockIdx.x * (long)blockDim.x + threadIdx.x; i < n;
         i += (long)gridDim.x * blockDim.x)
        deg[i] = 1.0f;  // self-loop
}

__global__ void deg_accum_kernel(const int* __restrict__ dst, float* __restrict__ deg, int E) {
    for (long i = blockIdx.x * (long)blockDim.x + threadIdx.x; i < E;
         i += (long)gridDim.x * blockDim.x)
        atomicAdd(&deg[dst[i]], 1.0f);
}

__global__ void rsqrt_kernel(float* __restrict__ d, int n) {
    for (long i = blockIdx.x * (long)blockDim.x + threadIdx.x; i < n;
         i += (long)gridDim.x * blockDim.x)
        d[i] = rsqrtf(d[i]);
}

// C[M,Nn] = A[M,K] @ B[K,Nn]; K % 16 == 0, Nn % 64 == 0; M tail guarded.
__global__ __launch_bounds__(256) void gemm64_kernel(const float* __restrict__ A,
                                                     const float* __restrict__ B,
                                                     float* __restrict__ C,
                                                     int M, int K, int Nn) {
    __shared__ float As[16][68];  // [k][m], pad keeps 16B alignment
    __shared__ float Bs[16][68];  // [k][n]
    const int tid = threadIdx.x;
    const int bm = blockIdx.x * 64;
    const int bn = blockIdx.y * 64;
    const int tr = tid >> 4, tc = tid & 15;        // 16x16 thread grid, 4x4 each
    const int lm = tid >> 2, lk4 = (tid & 3) << 2; // A loader
    const int lkb = tid >> 4, ln4 = (tid & 15) << 2; // B loader
    const int gm = bm + lm;

    float acc[4][4] = {{0.f, 0.f, 0.f, 0.f}, {0.f, 0.f, 0.f, 0.f},
                       {0.f, 0.f, 0.f, 0.f}, {0.f, 0.f, 0.f, 0.f}};

    for (int kk = 0; kk < K; kk += 16) {
        float4 av = make_float4(0.f, 0.f, 0.f, 0.f);
        if (gm < M) av = *(const float4*)(A + (size_t)gm * K + kk + lk4);
        float4 bv = *(const float4*)(B + (size_t)(kk + lkb) * Nn + bn + ln4);
        __syncthreads();
        As[lk4 + 0][lm] = av.x;
        As[lk4 + 1][lm] = av.y;
        As[lk4 + 2][lm] = av.z;
        As[lk4 + 3][lm] = av.w;
        *(float4*)&Bs[lkb][ln4] = bv;
        __syncthreads();
#pragma unroll
        for (int k = 0; k < 16; ++k) {
            float4 a4 = *(const float4*)&As[k][tr << 2];
            float4 b4 = *(const float4*)&Bs[k][tc << 2];
            float ar[4] = {a4.x, a4.y, a4.z, a4.w};
            float br[4] = {b4.x, b4.y, b4.z, b4.w};
#pragma unroll
            for (int i = 0; i < 4; ++i)
#pragma unroll
                for (int j = 0; j < 4; ++j) acc[i][j] = fmaf(ar[i], br[j], acc[i][j]);
        }
    }
#pragma unroll
    for (int i = 0; i < 4; ++i) {
        int row = bm + (tr << 2) + i;
        if (row < M) {
            float4 o = make_float4(acc[i][0], acc[i][1], acc[i][2], acc[i][3]);
            *(float4*)(C + (size_t)row * Nn + bn + (tc << 2)) = o;
        }
    }
}

// y[i,f] = bias[f] + t[i,f] * dinv[i]^2   (self-loop term; fully overwrites y)
__global__ void agg_init_kernel(const float* __restrict__ t, const float* __restrict__ dinv,
                                const float* __restrict__ bias, float* __restrict__ y,
                                long total, int hshift) {
    const int hm = (1 << hshift) - 1;
    for (long i = blockIdx.x * (long)blockDim.x + threadIdx.x; i < total;
         i += (long)gridDim.x * blockDim.x) {
        int node = (int)(i >> hshift);
        int f = (int)(i & hm);
        float dv = dinv[node];
        y[i] = bias[f] + t[i] * dv * dv;
    }
}

// y[dst] += t[src] * dinv[src]*dinv[dst]   per edge, per feature
__global__ void agg_edges_kernel(const int* __restrict__ src, const int* __restrict__ dst,
                                 const float* __restrict__ dinv, const float* __restrict__ t,
                                 float* __restrict__ y, int E, int hshift) {
    const int H = 1 << hshift;
    const int epb = blockDim.x >> hshift;
    const int el = threadIdx.x >> hshift;
    const int f = threadIdx.x & (H - 1);
    for (long e = blockIdx.x * (long)epb + el; e < E; e += (long)gridDim.x * epb) {
        int s = src[e], d = dst[e];
        float w = dinv[s] * dinv[d];
        atomicAdd(y + (size_t)d * H + f, t[(size_t)s * H + f] * w);
    }
}

__device__ __forceinline__ float elu1(float v) { return v > 0.f ? v : expm1f(v); }

__global__ void elu_kernel(float* __restrict__ y, long n4) {
    float4* p = (float4*)y;
    for (long i = blockIdx.x * (long)blockDim.x + threadIdx.x; i < n4;
         i += (long)gridDim.x * blockDim.x) {
        float4 v = p[i];
        v.x = elu1(v.x); v.y = elu1(v.y); v.z = elu1(v.z); v.w = elu1(v.w);
        p[i] = v;
    }
}

__global__ void elu_res_kernel(float* __restrict__ y, const float* __restrict__ r, long n4) {
    float4* p = (float4*)y;
    const float4* q = (const float4*)r;
    for (long i = blockIdx.x * (long)blockDim.x + threadIdx.x; i < n4;
         i += (long)gridDim.x * blockDim.x) {
        float4 v = p[i];
        float4 w = q[i];
        v.x = elu1(v.x + w.x); v.y = elu1(v.y + w.y);
        v.z = elu1(v.z + w.z); v.w = elu1(v.w + w.w);
        p[i] = v;
    }
}

extern "C" void kernel_launch(void* const* d_in, const int* in_sizes, int n_in,
                              void* d_out, int out_size, void* d_ws, size_t ws_size,
                              hipStream_t stream) {
    const float* x = (const float*)d_in[0];
    const void* ei_raw = d_in[1];
    const float* W1 = (const float*)d_in[2];
    const float* b1 = (const float*)d_in[3];
    const float* W2 = (const float*)d_in[4];
    const float* b2 = (const float*)d_in[5];
    const float* W3 = (const float*)d_in[6];
    const float* b3 = (const float*)d_in[7];
    float* out = (float*)d_out;

    const int H = in_sizes[3];            // 256
    const int F = in_sizes[2] / H;        // 512
    const int N = in_sizes[0] / F;        // 50000
    const int C = in_sizes[7];            // 64
    const int E = in_sizes[1] / 2;        // 800000
    const int hs = __builtin_ctz(H);
    const int cs = __builtin_ctz(C);

    // workspace layout
    char* ws = (char*)d_ws;
    size_t off = 0;
    auto take = [&](size_t bytes) -> char* {
        char* p = ws + off;
        off += (bytes + 255) & ~(size_t)255;
        return p;
    };
    float* dinv = (float*)take((size_t)N * 4);
    int* flag = (int*)take(4);
    float* t = (float*)take((size_t)N * H * 4);
    float* h1 = (float*)take((size_t)N * H * 4);
    float* h2 = (float*)take((size_t)N * H * 4);
    int* e32 = (int*)take((size_t)2 * E * 4);
    int* srcI = e32;
    int* dstI = e32 + E;
    (void)ws_size; (void)n_in; (void)out_size;

    const long totH = (long)N * H;
    const long totC = (long)N * C;

    // edge normalization + degrees
    detect_fmt_kernel<<<1, 64, 0, stream>>>((const unsigned*)ei_raw, N, flag);
    edges_to_i32_kernel<<<cdiv_i(2L * E, 256), 256, 0, stream>>>(ei_raw, e32, 2 * E, flag);
    deg_init_kernel<<<cdiv_i(N, 256), 256, 0, stream>>>(dinv, N);
    deg_accum_kernel<<<cdiv_i(E, 256), 256, 0, stream>>>(dstI, dinv, E);
    rsqrt_kernel<<<cdiv_i(N, 256), 256, 0, stream>>>(dinv, N);

    const int egrid = (int)min((long)E, 131072L);

    // ---- layer 1: h1 = elu(A_hat @ (x @ W1) + b1)
    gemm64_kernel<<<dim3(cdiv_i(N, 64), H / 64), 256, 0, stream>>>(x, W1, t, N, F, H);
    agg_init_kernel<<<cdiv_i(totH, 256), 256, 0, stream>>>(t, dinv, b1, h1, totH, hs);
    agg_edges_kernel<<<egrid, 256, 0, stream>>>(srcI, dstI, dinv, t, h1, E, hs);
    elu_kernel<<<cdiv_i(totH / 4, 256), 256, 0, stream>>>(h1, totH / 4);

    // ---- layer 2: h2 = elu(A_hat @ (h1 @ W2) + b2 + h1)
    gemm64_kernel<<<dim3(cdiv_i(N, 64), H / 64), 256, 0, stream>>>(h1, W2, t, N, H, H);
    agg_init_kernel<<<cdiv_i(totH, 256), 256, 0, stream>>>(t, dinv, b2, h2, totH, hs);
    agg_edges_kernel<<<egrid, 256, 0, stream>>>(srcI, dstI, dinv, t, h2, E, hs);
    elu_res_kernel<<<cdiv_i(totH / 4, 256), 256, 0, stream>>>(h2, h1, totH / 4);

    // ---- layer 3: out = A_hat @ (h2 @ W3) + b3
    gemm64_kernel<<<dim3(cdiv_i(N, 64), C / 64), 256, 0, stream>>>(h2, W3, t, N, H, C);
    agg_init_kernel<<<cdiv_i(totC, 256), 256, 0, stream>>>(t, dinv, b3, out, totC, cs);
    agg_edges_kernel<<<egrid, 256, 0, stream>>>(srcI, dstI, dinv, t, out, E, cs);
}

// Round 2
// 737.750 us; speedup vs baseline: 2.6239x; 2.6239x over previous
//
#include <hip/hip_runtime.h>
#include <cstdint>
#include <cstddef>

// ---------------------------------------------------------------------------
// GCN: 3 layers.  out = A_hat @ (h @ W) + b, A_hat = D^-1/2 (A+I) D^-1/2
// R1: CSR (by dst) built on-device each call; pull-based aggregation with
//     fused self-loop + bias + residual + ELU. No feature atomics.
// ---------------------------------------------------------------------------

static inline int cdiv_i(long a, long b) { return (int)((a + b - 1) / b); }

__global__ void detect_fmt_kernel(const unsigned int* __restrict__ raw, int n_nodes,
                                  int* __restrict__ flag) {
    if (blockIdx.x == 0 && threadIdx.x == 0) {
        int is64 = 1;
        for (int i = 0; i < 64; ++i) {
            unsigned lo = raw[2 * i], hi = raw[2 * i + 1];
            if (hi != 0u || lo >= (unsigned)n_nodes) { is64 = 0; break; }
        }
        *flag = is64;
    }
}

__global__ void edges_to_i32_kernel(const void* __restrict__ raw, int* __restrict__ out,
                                    int twoE, const int* __restrict__ flag) {
    const int f = *flag;
    for (long i = blockIdx.x * (long)blockDim.x + threadIdx.x; i < twoE;
         i += (long)gridDim.x * blockDim.x) {
        out[i] = f ? (int)(((const long long*)raw)[i]) : ((const int*)raw)[i];
    }
}

__global__ void zero_i32_kernel(int* __restrict__ p, int n) {
    for (long i = blockIdx.x * (long)blockDim.x + threadIdx.x; i < n;
         i += (long)gridDim.x * blockDim.x)
        p[i] = 0;
}

__global__ void hist_kernel(const int* __restrict__ dst, int* __restrict__ cnt, int E) {
    for (long i = blockIdx.x * (long)blockDim.x + threadIdx.x; i < E;
         i += (long)gridDim.x * blockDim.x)
        atomicAdd(&cnt[dst[i]], 1);
}

__global__ void dinv_kernel(const int* __restrict__ cnt, float* __restrict__ dinv, int n) {
    for (long i = blockIdx.x * (long)blockDim.x + threadIdx.x; i < n;
         i += (long)gridDim.x * blockDim.x)
        dinv[i] = rsqrtf((float)cnt[i] + 1.0f);  // +1 self-loop
}

// ---- exclusive scan over n ints: 1024 elems / block ----
__global__ __launch_bounds__(256) void scan1_kernel(const int* __restrict__ in,
                                                    int* __restrict__ out,
                                                    int* __restrict__ bsum, int n) {
    __shared__ int tsum[256];
    const int tid = threadIdx.x;
    const long base = (long)blockIdx.x * 1024 + (long)tid * 4;
    int v[4];
#pragma unroll
    for (int i = 0; i < 4; ++i) v[i] = (base + i < n) ? in[base + i] : 0;
    const int s = v[0] + v[1] + v[2] + v[3];
    tsum[tid] = s;
    __syncthreads();
    for (int off = 1; off < 256; off <<= 1) {
        int add = (tid >= off) ? tsum[tid - off] : 0;
        __syncthreads();
        tsum[tid] += add;
        __syncthreads();
    }
    int run = tsum[tid] - s;  // exclusive prefix of this thread's chunk
#pragma unroll
    for (int i = 0; i < 4; ++i) {
        if (base + i < n) out[base + i] = run;
        run += v[i];
    }
    if (tid == 255) bsum[blockIdx.x] = tsum[255];
}

__global__ void scan2_kernel(int* __restrict__ bsum, int nb) {
    __shared__ int lds[256];
    const int tid = threadIdx.x;
    int v = (tid < nb) ? bsum[tid] : 0;
    lds[tid] = v;
    __syncthreads();
    for (int off = 1; off < 256; off <<= 1) {
        int add = (tid >= off) ? lds[tid - off] : 0;
        __syncthreads();
        lds[tid] += add;
        __syncthreads();
    }
    if (tid < nb) bsum[tid] = lds[tid] - v;  // exclusive
}

__global__ __launch_bounds__(256) void scan3_kernel(int* __restrict__ out,
                                                    const int* __restrict__ bsum, int n) {
    const long base = (long)blockIdx.x * 1024 + (long)threadIdx.x * 4;
    const int add = bsum[blockIdx.x];
#pragma unroll
    for (int i = 0; i < 4; ++i)
        if (base + i < n) out[base + i] += add;
}

__global__ void set_int_kernel(int* __restrict__ p, int idx, int val) {
    if (blockIdx.x == 0 && threadIdx.x == 0) p[idx] = val;
}

__global__ void scatter_kernel(const int* __restrict__ src, const int* __restrict__ dst,
                               const int* __restrict__ row_ptr, int* __restrict__ fill,
                               int* __restrict__ col, int E) {
    for (long i = blockIdx.x * (long)blockDim.x + threadIdx.x; i < E;
         i += (long)gridDim.x * blockDim.x) {
        int d = dst[i];
        int p = row_ptr[d] + atomicAdd(&fill[d], 1);
        col[p] = src[i];
    }
}

// C[M,Nn] = A[M,K] @ B[K,Nn]; K % 16 == 0, Nn % 64 == 0; M tail guarded.
__global__ __launch_bounds__(256) void gemm64_kernel(const float* __restrict__ A,
                                                     const float* __restrict__ B,
                                                     float* __restrict__ C,
                                                     int M, int K, int Nn) {
    __shared__ float As[16][68];
    __shared__ float Bs[16][68];
    const int tid = threadIdx.x;
    const int bm = blockIdx.x * 64;
    const int bn = blockIdx.y * 64;
    const int tr = tid >> 4, tc = tid & 15;
    const int lm = tid >> 2, lk4 = (tid & 3) << 2;
    const int lkb = tid >> 4, ln4 = (tid & 15) << 2;
    const int gm = bm + lm;

    float acc[4][4] = {{0.f, 0.f, 0.f, 0.f}, {0.f, 0.f, 0.f, 0.f},
                       {0.f, 0.f, 0.f, 0.f}, {0.f, 0.f, 0.f, 0.f}};

    for (int kk = 0; kk < K; kk += 16) {
        float4 av = make_float4(0.f, 0.f, 0.f, 0.f);
        if (gm < M) av = *(const float4*)(A + (size_t)gm * K + kk + lk4);
        float4 bv = *(const float4*)(B + (size_t)(kk + lkb) * Nn + bn + ln4);
        __syncthreads();
        As[lk4 + 0][lm] = av.x;
        As[lk4 + 1][lm] = av.y;
        As[lk4 + 2][lm] = av.z;
        As[lk4 + 3][lm] = av.w;
        *(float4*)&Bs[lkb][ln4] = bv;
        __syncthreads();
#pragma unroll
        for (int k = 0; k < 16; ++k) {
            float4 a4 = *(const float4*)&As[k][tr << 2];
            float4 b4 = *(const float4*)&Bs[k][tc << 2];
            float ar[4] = {a4.x, a4.y, a4.z, a4.w};
            float br[4] = {b4.x, b4.y, b4.z, b4.w};
#pragma unroll
            for (int i = 0; i < 4; ++i)
#pragma unroll
                for (int j = 0; j < 4; ++j) acc[i][j] = fmaf(ar[i], br[j], acc[i][j]);
        }
    }
#pragma unroll
    for (int i = 0; i < 4; ++i) {
        int row = bm + (tr << 2) + i;
        if (row < M) {
            float4 o = make_float4(acc[i][0], acc[i][1], acc[i][2], acc[i][3]);
            *(float4*)(C + (size_t)row * Nn + bn + (tc << 2)) = o;
        }
    }
}

__device__ __forceinline__ float elu1(float v) { return v > 0.f ? v : expm1f(v); }

// Pull aggregation, one wave per node. VEC floats per lane (64*VEC = Hdim).
// MODE 0: y=elu(conv)  MODE 1: y=elu(conv+res)  MODE 2: y=conv
template <int VEC, int MODE>
__global__ __launch_bounds__(256) void agg_pull_kernel(
    const int* __restrict__ row_ptr, const int* __restrict__ col,
    const float* __restrict__ dinv, const float* __restrict__ t,
    const float* __restrict__ bias, const float* __restrict__ res,
    float* __restrict__ y, int Nn, int Hdim) {
    const int node = blockIdx.x * (blockDim.x >> 6) + (threadIdx.x >> 6);
    if (node >= Nn) return;
    const int lane = threadIdx.x & 63;
    const int f = lane * VEC;

    float acc[VEC];
#pragma unroll
    for (int i = 0; i < VEC; ++i) acc[i] = 0.f;

    const int s0 = row_ptr[node], s1 = row_ptr[node + 1];
    for (int e = s0; e < s1; ++e) {
        const int s = col[e];
        const float w = dinv[s];
        const float* ts = t + (size_t)s * Hdim + f;
        if (VEC == 4) {
            float4 v = *(const float4*)ts;
            acc[0] = fmaf(v.x, w, acc[0]);
            acc[1] = fmaf(v.y, w, acc[1]);
            acc[2] = fmaf(v.z, w, acc[2]);
            acc[3] = fmaf(v.w, w, acc[3]);
        } else {
            acc[0] = fmaf(*ts, w, acc[0]);
        }
    }

    const float dn = dinv[node];
    const float* tn = t + (size_t)node * Hdim + f;
    float o[VEC];
#pragma unroll
    for (int i = 0; i < VEC; ++i)
        o[i] = (acc[i] + tn[i] * dn) * dn + bias[f + i];

    if (MODE == 1) {
        const float* rn = res + (size_t)node * Hdim + f;
#pragma unroll
        for (int i = 0; i < VEC; ++i) o[i] += rn[i];
    }
    if (MODE <= 1) {
#pragma unroll
        for (int i = 0; i < VEC; ++i) o[i] = elu1(o[i]);
    }

    float* yn = y + (size_t)node * Hdim + f;
    if (VEC == 4) {
        *(float4*)yn = make_float4(o[0], o[1], o[2], o[3]);
    } else {
        *yn = o[0];
    }
}

extern "C" void kernel_launch(void* const* d_in, const int* in_sizes, int n_in,
                              void* d_out, int out_size, void* d_ws, size_t ws_size,
                              hipStream_t stream) {
    const float* x = (const float*)d_in[0];
    const void* ei_raw = d_in[1];
    const float* W1 = (const float*)d_in[2];
    const float* b1 = (const float*)d_in[3];
    const float* W2 = (const float*)d_in[4];
    const float* b2 = (const float*)d_in[5];
    const float* W3 = (const float*)d_in[6];
    const float* b3 = (const float*)d_in[7];
    float* out = (float*)d_out;

    const int H = in_sizes[3];       // 256
    const int F = in_sizes[2] / H;   // 512
    const int N = in_sizes[0] / F;   // 50000
    const int C = in_sizes[7];       // 64
    const int E = in_sizes[1] / 2;   // 800000

    // workspace layout
    char* ws = (char*)d_ws;
    size_t off = 0;
    auto take = [&](size_t bytes) -> char* {
        char* p = ws + off;
        off += (bytes + 255) & ~(size_t)255;
        return p;
    };
    float* dinv = (float*)take((size_t)N * 4);
    int* flag = (int*)take(4);
    float* t = (float*)take((size_t)N * H * 4);
    float* h1 = (float*)take((size_t)N * H * 4);
    float* h2 = (float*)take((size_t)N * H * 4);
    int* e32 = (int*)take((size_t)2 * E * 4);
    int* srcI = e32;
    int* dstI = e32 + E;
    int* col = (int*)take((size_t)E * 4);
    int* cnt = (int*)take((size_t)N * 4);
    int* row_ptr = (int*)take((size_t)(N + 1) * 4);
    int* fill = (int*)take((size_t)N * 4);
    int* bsum = (int*)take(256 * 4);
    (void)ws_size; (void)n_in; (void)out_size;

    const int nScanBlk = cdiv_i(N, 1024);  // 49 (<256 for scan2)

    // ---- edges + degrees + CSR ----
    detect_fmt_kernel<<<1, 64, 0, stream>>>((const unsigned*)ei_raw, N, flag);
    edges_to_i32_kernel<<<cdiv_i(2L * E, 256), 256, 0, stream>>>(ei_raw, e32, 2 * E, flag);
    zero_i32_kernel<<<cdiv_i(N, 256), 256, 0, stream>>>(cnt, N);
    hist_kernel<<<cdiv_i(E, 256), 256, 0, stream>>>(dstI, cnt, E);
    dinv_kernel<<<cdiv_i(N, 256), 256, 0, stream>>>(cnt, dinv, N);
    scan1_kernel<<<nScanBlk, 256, 0, stream>>>(cnt, row_ptr, bsum, N);
    scan2_kernel<<<1, 256, 0, stream>>>(bsum, nScanBlk);
    scan3_kernel<<<nScanBlk, 256, 0, stream>>>(row_ptr, bsum, N);
    set_int_kernel<<<1, 1, 0, stream>>>(row_ptr, N, E);
    zero_i32_kernel<<<cdiv_i(N, 256), 256, 0, stream>>>(fill, N);
    scatter_kernel<<<cdiv_i(E, 256), 256, 0, stream>>>(srcI, dstI, row_ptr, fill, col, E);

    const int aggGridH = cdiv_i(N, 4);  // 4 waves/block, 1 node/wave

    // ---- layer 1: h1 = elu(A_hat @ (x @ W1) + b1)
    gemm64_kernel<<<dim3(cdiv_i(N, 64), H / 64), 256, 0, stream>>>(x, W1, t, N, F, H);
    agg_pull_kernel<4, 0><<<aggGridH, 256, 0, stream>>>(row_ptr, col, dinv, t, b1,
                                                        nullptr, h1, N, H);

    // ---- layer 2: h2 = elu(A_hat @ (h1 @ W2) + b2 + h1)
    gemm64_kernel<<<dim3(cdiv_i(N, 64), H / 64), 256, 0, stream>>>(h1, W2, t, N, H, H);
    agg_pull_kernel<4, 1><<<aggGridH, 256, 0, stream>>>(row_ptr, col, dinv, t, b2,
                                                        h1, h2, N, H);

    // ---- layer 3: out = A_hat @ (h2 @ W3) + b3
    gemm64_kernel<<<dim3(cdiv_i(N, 64), C / 64), 256, 0, stream>>>(h2, W3, t, N, H, C);
    agg_pull_kernel<1, 2><<<aggGridH, 256, 0, stream>>>(row_ptr, col, dinv, t, b3,
                                                        nullptr, out, N, C);
}